// Round 7
// baseline (492.876 us; speedup 1.0000x reference)
//
#include <hip/hip_runtime.h>
#include <stdint.h>

#define NSEQ 64      // B*C
#define TT   256
#define FF   64
#define DM   128
#define DI   256
#define DS   16
#define DTR  8
#define XDBL 40      // DTR + 2*DS
#define LN_EPS 1e-5f

__device__ __forceinline__ float silu(float v) { return v / (1.f + __expf(-v)); }

// ============ kernel 1: input projection GEMM ============
__global__ __launch_bounds__(256) void k_input_proj(const float* __restrict__ x,
                                                    const float* __restrict__ w,
                                                    const float* __restrict__ b,
                                                    float* __restrict__ h) {
    __shared__ float As[FF][68];    // As[f][local_t]
    __shared__ float Bs[FF][132];   // Bs[f][dm]
    const int m0 = blockIdx.x * 64;
    const int n = m0 >> 8, t0 = m0 & 255;
    const int tid = threadIdx.x;
    {
        const int tq = tid & 15, f0 = tid >> 4;
#pragma unroll
        for (int i = 0; i < 4; ++i) {
            int f = f0 + 16 * i;
            float4 v = *(const float4*)&x[((size_t)n * FF + f) * TT + t0 + 4 * tq];
            *(float4*)&As[f][4 * tq] = v;
        }
#pragma unroll
        for (int i = 0; i < 8; ++i) {
            int col = f0 + 16 * i;
            float4 v = *(const float4*)&w[(size_t)col * FF + 4 * tq];
            Bs[4 * tq + 0][col] = v.x; Bs[4 * tq + 1][col] = v.y;
            Bs[4 * tq + 2][col] = v.z; Bs[4 * tq + 3][col] = v.w;
        }
    }
    __syncthreads();
    const int ty = tid >> 4, tx = tid & 15;
    float acc[4][8];
#pragma unroll
    for (int r = 0; r < 4; ++r)
#pragma unroll
        for (int c = 0; c < 8; ++c) acc[r][c] = 0.f;
#pragma unroll 8
    for (int k = 0; k < FF; ++k) {
        float4 a = *(float4*)&As[k][ty * 4];
        float4 b0 = *(float4*)&Bs[k][tx * 8];
        float4 b1 = *(float4*)&Bs[k][tx * 8 + 4];
        float av[4] = {a.x, a.y, a.z, a.w};
        float bv[8] = {b0.x, b0.y, b0.z, b0.w, b1.x, b1.y, b1.z, b1.w};
#pragma unroll
        for (int r = 0; r < 4; ++r)
#pragma unroll
            for (int c = 0; c < 8; ++c) acc[r][c] += av[r] * bv[c];
    }
#pragma unroll
    for (int r = 0; r < 4; ++r) {
        int row = m0 + ty * 4 + r;
        float4 o0, o1;
        o0.x = acc[r][0] + b[tx * 8 + 0]; o0.y = acc[r][1] + b[tx * 8 + 1];
        o0.z = acc[r][2] + b[tx * 8 + 2]; o0.w = acc[r][3] + b[tx * 8 + 3];
        o1.x = acc[r][4] + b[tx * 8 + 4]; o1.y = acc[r][5] + b[tx * 8 + 5];
        o1.z = acc[r][6] + b[tx * 8 + 6]; o1.w = acc[r][7] + b[tx * 8 + 7];
        *(float4*)&h[(size_t)row * DM + tx * 8] = o0;
        *(float4*)&h[(size_t)row * DM + tx * 8 + 4] = o1;
    }
}

// ============ kernel 2: in_proj GEMM ============
__global__ __launch_bounds__(256) void k_in_proj(const float* __restrict__ h,
                                                 const float* __restrict__ ipw,
                                                 float* __restrict__ xz, int l) {
    __shared__ float As[64][68];
    __shared__ float Bs[64][68];
    const int m0 = (blockIdx.x >> 3) * 64;
    const int n0 = (blockIdx.x & 7) * 64;
    const int tid = threadIdx.x;
    const int ty = tid >> 4, tx = tid & 15;
    const float* wbase = ipw + (size_t)l * 2 * DI * DM;
    float acc[4][4];
#pragma unroll
    for (int r = 0; r < 4; ++r)
#pragma unroll
        for (int c = 0; c < 4; ++c) acc[r][c] = 0.f;

    for (int k0 = 0; k0 < DM; k0 += 64) {
        const int kq = tid & 15, r0 = tid >> 4;
#pragma unroll
        for (int i = 0; i < 4; ++i) {
            int row = r0 + 16 * i;
            float4 v = *(const float4*)&h[(size_t)(m0 + row) * DM + k0 + 4 * kq];
            As[4 * kq + 0][row] = v.x; As[4 * kq + 1][row] = v.y;
            As[4 * kq + 2][row] = v.z; As[4 * kq + 3][row] = v.w;
            float4 wv = *(const float4*)&wbase[(size_t)(n0 + row) * DM + k0 + 4 * kq];
            Bs[4 * kq + 0][row] = wv.x; Bs[4 * kq + 1][row] = wv.y;
            Bs[4 * kq + 2][row] = wv.z; Bs[4 * kq + 3][row] = wv.w;
        }
        __syncthreads();
#pragma unroll 8
        for (int k = 0; k < 64; ++k) {
            float4 a = *(float4*)&As[k][ty * 4];
            float4 b = *(float4*)&Bs[k][tx * 4];
            float av[4] = {a.x, a.y, a.z, a.w};
            float bv[4] = {b.x, b.y, b.z, b.w};
#pragma unroll
            for (int r = 0; r < 4; ++r)
#pragma unroll
                for (int c = 0; c < 4; ++c) acc[r][c] += av[r] * bv[c];
        }
        __syncthreads();
    }
#pragma unroll
    for (int r = 0; r < 4; ++r) {
        int row = m0 + ty * 4 + r;
        float4 o = {acc[r][0], acc[r][1], acc[r][2], acc[r][3]};
        *(float4*)&xz[(size_t)row * (2 * DI) + n0 + tx * 4] = o;
    }
}

// ============ kernel 3: conv(recompute)+silu + x_dbl + delta -> dlt buffer ============
// 320 threads; conv from raw xi rows nt-3..nt
__global__ __launch_bounds__(320) void k_xd(const float* __restrict__ xz,
                                            const float* __restrict__ cw,
                                            const float* __restrict__ cb,
                                            const float* __restrict__ xpw,
                                            const float* __restrict__ dtw,
                                            const float* __restrict__ dtb,
                                            float* __restrict__ xdbl,
                                            float* __restrict__ dlt, int l) {
    __shared__ float us[DI];
    __shared__ float xd[XDBL];
    const int nt = blockIdx.x, tid = threadIdx.x;
    const int t = nt & 255;
    if (tid < DI) {
        const float* wr = cw + ((size_t)l * DI + tid) * 4;
        float acc = cb[l * DI + tid];
#pragma unroll
        for (int j = 0; j < 4; ++j) {
            int back = 3 - j;
            if (t - back >= 0)
                acc += xz[(size_t)(nt - back) * 512 + tid] * wr[j];
        }
        us[tid] = silu(acc);
    }
    __syncthreads();
    {
        const int g = tid >> 3, i = tid & 7;
        const float* wr = xpw + ((size_t)l * XDBL + g) * DI;
        float p = 0.f;
#pragma unroll
        for (int q = 0; q < 8; ++q) {
            int k = i * 4 + 32 * q;
            float4 uv = *(float4*)&us[k];
            float4 wv = *(const float4*)&wr[k];
            p += uv.x * wv.x + uv.y * wv.y + uv.z * wv.z + uv.w * wv.w;
        }
        p += __shfl_xor(p, 1); p += __shfl_xor(p, 2); p += __shfl_xor(p, 4);
        if (i == 0) { xd[g] = p; xdbl[(size_t)nt * XDBL + g] = p; }
    }
    __syncthreads();
    if (tid < DI) {
        const float* dwr = dtw + ((size_t)l * DI + tid) * DTR;
        float a = dtb[l * DI + tid];
#pragma unroll
        for (int r = 0; r < DTR; ++r) a += xd[r] * dwr[r];
        float sp = (a > 20.f) ? a : log1pf(__expf(a));
        dlt[(size_t)nt * DI + tid] = sp;
    }
}

// ============ kernel 4: fused conv+silu + selective scan + D skip + silu(z) gate ====
// grid = NSEQ*8 (n, d-eighth: 32 channels), block = 256 = 32 ch x 8 state-groups of 2
// dly: delta in, gated y out (same buffer; writes trail prefetch reads)
__global__ __launch_bounds__(256) void k_scan(const float* __restrict__ xz,
                                              float* __restrict__ dly,
                                              const float* __restrict__ xdbl,
                                              const float* __restrict__ alog,
                                              const float* __restrict__ Dvec,
                                              const float* __restrict__ cw,
                                              const float* __restrict__ cb, int l) {
    const int n = blockIdx.x >> 3;
    const int d = (blockIdx.x & 7) * 32 + (threadIdx.x >> 3);
    const int sg = threadIdx.x & 7;          // states sg*2, sg*2+1
    __shared__ float Bs[TT * DS];
    __shared__ float Cs[TT * DS];
    for (int i = threadIdx.x; i < TT * 4; i += 256) {
        int t = i >> 2, sq = i & 3;
        const float* row = xdbl + ((size_t)n * TT + t) * XDBL;
        *(float4*)&Bs[t * DS + 4 * sq] = *(const float4*)&row[DTR + 4 * sq];
        *(float4*)&Cs[t * DS + 4 * sq] = *(const float4*)&row[DTR + DS + 4 * sq];
    }
    __syncthreads();
    float2 av = *(const float2*)&alog[((size_t)l * DI + d) * DS + sg * 2];
    const float A0 = -__expf(av.x), A1 = -__expf(av.y);
    const float Dv = Dvec[l * DI + d];
    const float4 cv = *(const float4*)&cw[((size_t)l * DI + d) * 4];
    const float cbv = cb[l * DI + d];
    float h0 = 0.f, h1 = 0.f;
    float xm3 = 0.f, xm2 = 0.f, xm1 = 0.f;   // causal conv history (zero-pad)

    const float* xi_p = xz + (size_t)n * TT * 512 + d;
    const float* zv_p = xi_p + 256;
    float* dl_p = dly + (size_t)n * TT * DI + d;

    float pX[8], pZ[8], pD[8];
#pragma unroll
    for (int j = 0; j < 8; ++j) {
        pX[j] = xi_p[(size_t)j * 512];
        pZ[j] = zv_p[(size_t)j * 512];
        pD[j] = dl_p[(size_t)j * DI];
    }
    for (int tb = 0; tb < TT; tb += 8) {
        float cX[8], cU[8], cZ[8];
#pragma unroll
        for (int j = 0; j < 8; ++j) { cX[j] = pX[j]; cU[j] = pD[j]; cZ[j] = pZ[j]; }
        const int tn0 = (tb + 8) & 255;      // wraps on last group; values unused
#pragma unroll
        for (int j = 0; j < 8; ++j) {
            size_t tn = (size_t)(tn0 + j);
            pX[j] = xi_p[tn * 512];
            pZ[j] = zv_p[tn * 512];
            pD[j] = dl_p[tn * DI];
        }
#pragma unroll
        for (int j = 0; j < 8; ++j) {
            const int t = tb + j;
            // conv + silu (in registers)
            float xc = cbv + cv.x * xm3 + cv.y * xm2 + cv.z * xm1 + cv.w * cX[j];
            xm3 = xm2; xm2 = xm1; xm1 = cX[j];
            float uv = silu(xc);
            float dlt = cU[j];
            float du = dlt * uv;
            const float* bt = Bs + t * DS + sg * 2;
            const float* ct = Cs + t * DS + sg * 2;
            float dA0 = __expf(dlt * A0), dA1 = __expf(dlt * A1);
            h0 = dA0 * h0 + du * bt[0];
            h1 = dA1 * h1 + du * bt[1];
            float y = h0 * ct[0] + h1 * ct[1];
            y += __shfl_xor(y, 1);
            y += __shfl_xor(y, 2);
            y += __shfl_xor(y, 4);
            if (sg == 0)
                dl_p[(size_t)t * DI] = (y + uv * Dv) * silu(cZ[j]);
        }
    }
}

// ============ kernel 5: out_proj GEMM + residual + layernorm ============
__global__ __launch_bounds__(256) void k_outproj_ln(const float* __restrict__ y,
                                                    const float* __restrict__ opw,
                                                    float* __restrict__ h,
                                                    const float* __restrict__ nw,
                                                    const float* __restrict__ nb, int l) {
    __shared__ float As[64][68];
    __shared__ float Bs[64][132];
    const int m0 = blockIdx.x * 64;
    const int tid = threadIdx.x;
    const int ty = tid >> 4, tx = tid & 15;
    const float* wbase = opw + (size_t)l * DM * DI;
    float acc[4][8];
#pragma unroll
    for (int r = 0; r < 4; ++r)
#pragma unroll
        for (int c = 0; c < 8; ++c) acc[r][c] = 0.f;

    for (int k0 = 0; k0 < DI; k0 += 64) {
        const int kq = tid & 15, r0 = tid >> 4;
#pragma unroll
        for (int i = 0; i < 4; ++i) {
            int row = r0 + 16 * i;
            float4 v = *(const float4*)&y[(size_t)(m0 + row) * DI + k0 + 4 * kq];
            As[4 * kq + 0][row] = v.x; As[4 * kq + 1][row] = v.y;
            As[4 * kq + 2][row] = v.z; As[4 * kq + 3][row] = v.w;
        }
#pragma unroll
        for (int i = 0; i < 8; ++i) {
            int col = r0 + 16 * i;
            float4 wv = *(const float4*)&wbase[(size_t)col * DI + k0 + 4 * kq];
            Bs[4 * kq + 0][col] = wv.x; Bs[4 * kq + 1][col] = wv.y;
            Bs[4 * kq + 2][col] = wv.z; Bs[4 * kq + 3][col] = wv.w;
        }
        __syncthreads();
#pragma unroll 8
        for (int k = 0; k < 64; ++k) {
            float4 a = *(float4*)&As[k][ty * 4];
            float4 b0 = *(float4*)&Bs[k][tx * 8];
            float4 b1 = *(float4*)&Bs[k][tx * 8 + 4];
            float av[4] = {a.x, a.y, a.z, a.w};
            float bv[8] = {b0.x, b0.y, b0.z, b0.w, b1.x, b1.y, b1.z, b1.w};
#pragma unroll
            for (int r = 0; r < 4; ++r)
#pragma unroll
                for (int c = 0; c < 8; ++c) acc[r][c] += av[r] * bv[c];
        }
        __syncthreads();
    }
#pragma unroll
    for (int r = 0; r < 4; ++r) {
        int row = m0 + ty * 4 + r;
        float4 h0 = *(float4*)&h[(size_t)row * DM + tx * 8];
        float4 h1 = *(float4*)&h[(size_t)row * DM + tx * 8 + 4];
        float v[8] = {acc[r][0] + h0.x, acc[r][1] + h0.y, acc[r][2] + h0.z, acc[r][3] + h0.w,
                      acc[r][4] + h1.x, acc[r][5] + h1.y, acc[r][6] + h1.z, acc[r][7] + h1.w};
        float s = 0.f, q = 0.f;
#pragma unroll
        for (int c = 0; c < 8; ++c) { s += v[c]; q += v[c] * v[c]; }
#pragma unroll
        for (int o = 1; o < 16; o <<= 1) { s += __shfl_xor(s, o); q += __shfl_xor(q, o); }
        float mu = s * (1.f / DM);
        float var = q * (1.f / DM) - mu * mu;
        float rs = rsqrtf(var + LN_EPS);
        float4 o0, o1;
        o0.x = (v[0] - mu) * rs * nw[l * DM + tx * 8 + 0] + nb[l * DM + tx * 8 + 0];
        o0.y = (v[1] - mu) * rs * nw[l * DM + tx * 8 + 1] + nb[l * DM + tx * 8 + 1];
        o0.z = (v[2] - mu) * rs * nw[l * DM + tx * 8 + 2] + nb[l * DM + tx * 8 + 2];
        o0.w = (v[3] - mu) * rs * nw[l * DM + tx * 8 + 3] + nb[l * DM + tx * 8 + 3];
        o1.x = (v[4] - mu) * rs * nw[l * DM + tx * 8 + 4] + nb[l * DM + tx * 8 + 4];
        o1.y = (v[5] - mu) * rs * nw[l * DM + tx * 8 + 5] + nb[l * DM + tx * 8 + 5];
        o1.z = (v[6] - mu) * rs * nw[l * DM + tx * 8 + 6] + nb[l * DM + tx * 8 + 6];
        o1.w = (v[7] - mu) * rs * nw[l * DM + tx * 8 + 7] + nb[l * DM + tx * 8 + 7];
        *(float4*)&h[(size_t)row * DM + tx * 8] = o0;
        *(float4*)&h[(size_t)row * DM + tx * 8 + 4] = o1;
    }
}

// ============ kernel 6: final layernorm + mean over T (parallel tokens) ============
__global__ __launch_bounds__(256) void k_final(const float* __restrict__ h,
                                               const float* __restrict__ ow,
                                               const float* __restrict__ ob,
                                               float* __restrict__ out) {
    const int n = blockIdx.x >> 2;
    const int quarter = blockIdx.x & 3;
    const int wave = threadIdx.x >> 6, lane = threadIdx.x & 63;
    const float w0 = ow[lane], w1 = ow[lane + 64];
    const float b0 = ob[lane], b1 = ob[lane + 64];
    float a0 = 0.f, a1 = 0.f;
    const int t0 = quarter * 64 + wave * 16;
#pragma unroll 4
    for (int i = 0; i < 16; ++i) {
        const float* row = h + ((size_t)n * TT + t0 + i) * DM;
        float v0 = row[lane], v1 = row[lane + 64];
        float s = v0 + v1, q = v0 * v0 + v1 * v1;
#pragma unroll
        for (int o = 1; o < 64; o <<= 1) { s += __shfl_xor(s, o); q += __shfl_xor(q, o); }
        float mu = s * (1.f / DM);
        float var = q * (1.f / DM) - mu * mu;
        float rs = rsqrtf(var + LN_EPS);
        a0 += (v0 - mu) * rs * w0 + b0;
        a1 += (v1 - mu) * rs * w1 + b1;
    }
    atomicAdd(&out[n * DM + lane], a0 * (1.f / TT));
    atomicAdd(&out[n * DM + lane + 64], a1 * (1.f / TT));
}

extern "C" void kernel_launch(void* const* d_in, const int* in_sizes, int n_in,
                              void* d_out, int out_size, void* d_ws, size_t ws_size,
                              hipStream_t stream) {
    const float* x     = (const float*)d_in[0];
    const float* inp_w = (const float*)d_in[1];
    const float* inp_b = (const float*)d_in[2];
    const float* ipw   = (const float*)d_in[3];
    const float* cw    = (const float*)d_in[4];
    const float* cb    = (const float*)d_in[5];
    const float* xpw   = (const float*)d_in[6];
    const float* dtw   = (const float*)d_in[7];
    const float* dtb   = (const float*)d_in[8];
    const float* alog  = (const float*)d_in[9];
    const float* Dv    = (const float*)d_in[10];
    const float* opw   = (const float*)d_in[11];
    const float* nw    = (const float*)d_in[12];
    const float* nb    = (const float*)d_in[13];
    const float* onw   = (const float*)d_in[14];
    const float* onb   = (const float*)d_in[15];

    float* base = (float*)d_ws;
    const size_t NT = (size_t)NSEQ * TT;
    float* h    = base;                 // NT*128
    float* xz   = h + NT * DM;          // NT*512  [xi raw | z]
    float* dlt  = xz + NT * 2 * DI;     // NT*256  delta in, gated y out
    float* xdbl = dlt + NT * DI;        // NT*40

    k_input_proj<<<NT / 64, 256, 0, stream>>>(x, inp_w, inp_b, h);
    for (int l = 0; l < 2; ++l) {
        k_in_proj<<<(NT / 64) * 8, 256, 0, stream>>>(h, ipw, xz, l);
        k_xd<<<NT, 320, 0, stream>>>(xz, cw, cb, xpw, dtw, dtb, xdbl, dlt, l);
        k_scan<<<NSEQ * 8, 256, 0, stream>>>(xz, dlt, xdbl, alog, Dv, cw, cb, l);
        k_outproj_ln<<<NT / 64, 256, 0, stream>>>(dlt, opw, h, nw, nb, l);
    }
    hipMemsetAsync(d_out, 0, (size_t)out_size * sizeof(float), stream);
    k_final<<<NSEQ * 4, 256, 0, stream>>>(h, onw, onb, (float*)d_out);
}

// Round 8
// 472.461 us; speedup vs baseline: 1.0432x; 1.0432x over previous
//
#include <hip/hip_runtime.h>
#include <stdint.h>

#define NSEQ 64      // B*C
#define TT   256
#define FF   64
#define DM   128
#define DI   256
#define DS   16
#define DTR  8
#define XDBL 40      // DTR + 2*DS
#define LN_EPS 1e-5f

__device__ __forceinline__ float silu(float v) { return v / (1.f + __expf(-v)); }

// ============ kernel 1: input projection GEMM ============
__global__ __launch_bounds__(256) void k_input_proj(const float* __restrict__ x,
                                                    const float* __restrict__ w,
                                                    const float* __restrict__ b,
                                                    float* __restrict__ h) {
    __shared__ float As[FF][68];    // As[f][local_t]
    __shared__ float Bs[FF][132];   // Bs[f][dm]
    const int m0 = blockIdx.x * 64;
    const int n = m0 >> 8, t0 = m0 & 255;
    const int tid = threadIdx.x;
    {
        const int tq = tid & 15, f0 = tid >> 4;
#pragma unroll
        for (int i = 0; i < 4; ++i) {
            int f = f0 + 16 * i;
            float4 v = *(const float4*)&x[((size_t)n * FF + f) * TT + t0 + 4 * tq];
            *(float4*)&As[f][4 * tq] = v;
        }
#pragma unroll
        for (int i = 0; i < 8; ++i) {
            int col = f0 + 16 * i;
            float4 v = *(const float4*)&w[(size_t)col * FF + 4 * tq];
            Bs[4 * tq + 0][col] = v.x; Bs[4 * tq + 1][col] = v.y;
            Bs[4 * tq + 2][col] = v.z; Bs[4 * tq + 3][col] = v.w;
        }
    }
    __syncthreads();
    const int ty = tid >> 4, tx = tid & 15;
    float acc[4][8];
#pragma unroll
    for (int r = 0; r < 4; ++r)
#pragma unroll
        for (int c = 0; c < 8; ++c) acc[r][c] = 0.f;
#pragma unroll 8
    for (int k = 0; k < FF; ++k) {
        float4 a = *(float4*)&As[k][ty * 4];
        float4 b0 = *(float4*)&Bs[k][tx * 8];
        float4 b1 = *(float4*)&Bs[k][tx * 8 + 4];
        float av[4] = {a.x, a.y, a.z, a.w};
        float bv[8] = {b0.x, b0.y, b0.z, b0.w, b1.x, b1.y, b1.z, b1.w};
#pragma unroll
        for (int r = 0; r < 4; ++r)
#pragma unroll
            for (int c = 0; c < 8; ++c) acc[r][c] += av[r] * bv[c];
    }
#pragma unroll
    for (int r = 0; r < 4; ++r) {
        int row = m0 + ty * 4 + r;
        float4 o0, o1;
        o0.x = acc[r][0] + b[tx * 8 + 0]; o0.y = acc[r][1] + b[tx * 8 + 1];
        o0.z = acc[r][2] + b[tx * 8 + 2]; o0.w = acc[r][3] + b[tx * 8 + 3];
        o1.x = acc[r][4] + b[tx * 8 + 4]; o1.y = acc[r][5] + b[tx * 8 + 5];
        o1.z = acc[r][6] + b[tx * 8 + 6]; o1.w = acc[r][7] + b[tx * 8 + 7];
        *(float4*)&h[(size_t)row * DM + tx * 8] = o0;
        *(float4*)&h[(size_t)row * DM + tx * 8 + 4] = o1;
    }
}

// ============ kernel 2: in_proj GEMM ============
__global__ __launch_bounds__(256) void k_in_proj(const float* __restrict__ h,
                                                 const float* __restrict__ ipw,
                                                 float* __restrict__ xz, int l) {
    __shared__ float As[64][68];
    __shared__ float Bs[64][68];
    const int m0 = (blockIdx.x >> 3) * 64;
    const int n0 = (blockIdx.x & 7) * 64;
    const int tid = threadIdx.x;
    const int ty = tid >> 4, tx = tid & 15;
    const float* wbase = ipw + (size_t)l * 2 * DI * DM;
    float acc[4][4];
#pragma unroll
    for (int r = 0; r < 4; ++r)
#pragma unroll
        for (int c = 0; c < 4; ++c) acc[r][c] = 0.f;

    for (int k0 = 0; k0 < DM; k0 += 64) {
        const int kq = tid & 15, r0 = tid >> 4;
#pragma unroll
        for (int i = 0; i < 4; ++i) {
            int row = r0 + 16 * i;
            float4 v = *(const float4*)&h[(size_t)(m0 + row) * DM + k0 + 4 * kq];
            As[4 * kq + 0][row] = v.x; As[4 * kq + 1][row] = v.y;
            As[4 * kq + 2][row] = v.z; As[4 * kq + 3][row] = v.w;
            float4 wv = *(const float4*)&wbase[(size_t)(n0 + row) * DM + k0 + 4 * kq];
            Bs[4 * kq + 0][row] = wv.x; Bs[4 * kq + 1][row] = wv.y;
            Bs[4 * kq + 2][row] = wv.z; Bs[4 * kq + 3][row] = wv.w;
        }
        __syncthreads();
#pragma unroll 8
        for (int k = 0; k < 64; ++k) {
            float4 a = *(float4*)&As[k][ty * 4];
            float4 b = *(float4*)&Bs[k][tx * 4];
            float av[4] = {a.x, a.y, a.z, a.w};
            float bv[4] = {b.x, b.y, b.z, b.w};
#pragma unroll
            for (int r = 0; r < 4; ++r)
#pragma unroll
                for (int c = 0; c < 4; ++c) acc[r][c] += av[r] * bv[c];
        }
        __syncthreads();
    }
#pragma unroll
    for (int r = 0; r < 4; ++r) {
        int row = m0 + ty * 4 + r;
        float4 o = {acc[r][0], acc[r][1], acc[r][2], acc[r][3]};
        *(float4*)&xz[(size_t)row * (2 * DI) + n0 + tx * 4] = o;
    }
}

// ============ kernel 3: causal depthwise conv + silu -> u ============
__global__ __launch_bounds__(256) void k_conv(const float* __restrict__ xz,
                                              const float* __restrict__ cw,
                                              const float* __restrict__ cb,
                                              float* __restrict__ u, int l) {
    int idx = blockIdx.x * 256 + threadIdx.x;
    int d = idx & (DI - 1);
    int nt = idx >> 8;
    int t = nt & 255;
    const float* wr = cw + ((size_t)l * DI + d) * 4;
    float acc = cb[l * DI + d];
#pragma unroll
    for (int j = 0; j < 4; ++j) {
        int back = 3 - j;
        if (t - back >= 0)
            acc += xz[(size_t)(nt - back) * (2 * DI) + d] * wr[j];
    }
    u[(size_t)nt * DI + d] = silu(acc);
}

// ============ kernel 4: x_dbl + delta (delta -> xi slot of xz) ============
__global__ __launch_bounds__(320) void k_xd(const float* __restrict__ u,
                                            const float* __restrict__ xpw,
                                            const float* __restrict__ dtw,
                                            const float* __restrict__ dtb,
                                            float* __restrict__ xdbl,
                                            float* __restrict__ xz, int l) {
    __shared__ float us[DI];
    __shared__ float xd[XDBL];
    const int nt = blockIdx.x, tid = threadIdx.x;
    if (tid < 64)
        *(float4*)&us[tid * 4] = *(const float4*)&u[(size_t)nt * DI + tid * 4];
    __syncthreads();
    {
        const int g = tid >> 3, i = tid & 7;
        const float* wr = xpw + ((size_t)l * XDBL + g) * DI;
        float p = 0.f;
#pragma unroll
        for (int q = 0; q < 8; ++q) {
            int k = i * 4 + 32 * q;
            float4 uv = *(float4*)&us[k];
            float4 wv = *(const float4*)&wr[k];
            p += uv.x * wv.x + uv.y * wv.y + uv.z * wv.z + uv.w * wv.w;
        }
        p += __shfl_xor(p, 1); p += __shfl_xor(p, 2); p += __shfl_xor(p, 4);
        if (i == 0) { xd[g] = p; xdbl[(size_t)nt * XDBL + g] = p; }
    }
    __syncthreads();
    if (tid < DI) {
        const float* dwr = dtw + ((size_t)l * DI + tid) * DTR;
        float a = dtb[l * DI + tid];
#pragma unroll
        for (int r = 0; r < DTR; ++r) a += xd[r] * dwr[r];
        float sp = (a > 20.f) ? a : log1pf(__expf(a));
        xz[(size_t)nt * (2 * DI) + tid] = sp;
    }
}

// ============ kernel 5: selective scan, state-split x8 + depth-8 register prefetch ==
// grid = NSEQ*8 (n, d-eighth: 32 channels), block = 256 = 32 ch x 8 state-groups of 2
// delta read from xi slot of xz; gated y written over u (writes trail prefetch reads)
__global__ __launch_bounds__(256) void k_scan(const float* __restrict__ xz,
                                              float* __restrict__ u,
                                              const float* __restrict__ xdbl,
                                              const float* __restrict__ alog,
                                              const float* __restrict__ Dvec, int l) {
    const int n = blockIdx.x >> 3;
    const int d = (blockIdx.x & 7) * 32 + (threadIdx.x >> 3);
    const int sg = threadIdx.x & 7;          // states sg*2, sg*2+1
    __shared__ float Bs[TT * DS];
    __shared__ float Cs[TT * DS];
    for (int i = threadIdx.x; i < TT * 4; i += 256) {
        int t = i >> 2, sq = i & 3;
        const float* row = xdbl + ((size_t)n * TT + t) * XDBL;
        *(float4*)&Bs[t * DS + 4 * sq] = *(const float4*)&row[DTR + 4 * sq];
        *(float4*)&Cs[t * DS + 4 * sq] = *(const float4*)&row[DTR + DS + 4 * sq];
    }
    __syncthreads();
    float2 av = *(const float2*)&alog[((size_t)l * DI + d) * DS + sg * 2];
    const float A0 = -__expf(av.x), A1 = -__expf(av.y);
    const float Dv = Dvec[l * DI + d];
    float h0 = 0.f, h1 = 0.f;

    const float* dlt_p = xz + (size_t)n * TT * (2 * DI) + d;
    const float* zv_p  = dlt_p + DI;
    const float* uv_p  = u + (size_t)n * TT * DI + d;

    float pD[8], pU[8], pZ[8];
#pragma unroll
    for (int j = 0; j < 8; ++j) {
        pD[j] = dlt_p[(size_t)j * (2 * DI)];
        pZ[j] = zv_p[(size_t)j * (2 * DI)];
        pU[j] = uv_p[(size_t)j * DI];
    }
    for (int tb = 0; tb < TT; tb += 8) {
        float cD[8], cU[8], cZ[8];
#pragma unroll
        for (int j = 0; j < 8; ++j) { cD[j] = pD[j]; cU[j] = pU[j]; cZ[j] = pZ[j]; }
        const int tn0 = (tb + 8) & 255;      // wraps on last group; values unused
#pragma unroll
        for (int j = 0; j < 8; ++j) {
            size_t tn = (size_t)(tn0 + j);
            pD[j] = dlt_p[tn * (2 * DI)];
            pZ[j] = zv_p[tn * (2 * DI)];
            pU[j] = uv_p[tn * DI];
        }
#pragma unroll
        for (int j = 0; j < 8; ++j) {
            const int t = tb + j;
            float dlt = cD[j], uv = cU[j];
            float du = dlt * uv;
            const float* bt = Bs + t * DS + sg * 2;
            const float* ct = Cs + t * DS + sg * 2;
            float dA0 = __expf(dlt * A0), dA1 = __expf(dlt * A1);
            h0 = dA0 * h0 + du * bt[0];
            h1 = dA1 * h1 + du * bt[1];
            float y = h0 * ct[0] + h1 * ct[1];
            y += __shfl_xor(y, 1);
            y += __shfl_xor(y, 2);
            y += __shfl_xor(y, 4);
            if (sg == 0)
                u[((size_t)n * TT + t) * DI + d] = (y + uv * Dv) * silu(cZ[j]);
        }
    }
}

// ============ kernel 6: out_proj GEMM + residual + layernorm ============
__global__ __launch_bounds__(256) void k_outproj_ln(const float* __restrict__ y,
                                                    const float* __restrict__ opw,
                                                    float* __restrict__ h,
                                                    const float* __restrict__ nw,
                                                    const float* __restrict__ nb, int l) {
    __shared__ float As[64][68];
    __shared__ float Bs[64][132];
    const int m0 = blockIdx.x * 64;
    const int tid = threadIdx.x;
    const int ty = tid >> 4, tx = tid & 15;
    const float* wbase = opw + (size_t)l * DM * DI;
    float acc[4][8];
#pragma unroll
    for (int r = 0; r < 4; ++r)
#pragma unroll
        for (int c = 0; c < 8; ++c) acc[r][c] = 0.f;

    for (int k0 = 0; k0 < DI; k0 += 64) {
        const int kq = tid & 15, r0 = tid >> 4;
#pragma unroll
        for (int i = 0; i < 4; ++i) {
            int row = r0 + 16 * i;
            float4 v = *(const float4*)&y[(size_t)(m0 + row) * DI + k0 + 4 * kq];
            As[4 * kq + 0][row] = v.x; As[4 * kq + 1][row] = v.y;
            As[4 * kq + 2][row] = v.z; As[4 * kq + 3][row] = v.w;
        }
#pragma unroll
        for (int i = 0; i < 8; ++i) {
            int col = r0 + 16 * i;
            float4 wv = *(const float4*)&wbase[(size_t)col * DI + k0 + 4 * kq];
            Bs[4 * kq + 0][col] = wv.x; Bs[4 * kq + 1][col] = wv.y;
            Bs[4 * kq + 2][col] = wv.z; Bs[4 * kq + 3][col] = wv.w;
        }
        __syncthreads();
#pragma unroll 8
        for (int k = 0; k < 64; ++k) {
            float4 a = *(float4*)&As[k][ty * 4];
            float4 b0 = *(float4*)&Bs[k][tx * 8];
            float4 b1 = *(float4*)&Bs[k][tx * 8 + 4];
            float av[4] = {a.x, a.y, a.z, a.w};
            float bv[8] = {b0.x, b0.y, b0.z, b0.w, b1.x, b1.y, b1.z, b1.w};
#pragma unroll
            for (int r = 0; r < 4; ++r)
#pragma unroll
                for (int c = 0; c < 8; ++c) acc[r][c] += av[r] * bv[c];
        }
        __syncthreads();
    }
#pragma unroll
    for (int r = 0; r < 4; ++r) {
        int row = m0 + ty * 4 + r;
        float4 h0 = *(float4*)&h[(size_t)row * DM + tx * 8];
        float4 h1 = *(float4*)&h[(size_t)row * DM + tx * 8 + 4];
        float v[8] = {acc[r][0] + h0.x, acc[r][1] + h0.y, acc[r][2] + h0.z, acc[r][3] + h0.w,
                      acc[r][4] + h1.x, acc[r][5] + h1.y, acc[r][6] + h1.z, acc[r][7] + h1.w};
        float s = 0.f, q = 0.f;
#pragma unroll
        for (int c = 0; c < 8; ++c) { s += v[c]; q += v[c] * v[c]; }
#pragma unroll
        for (int o = 1; o < 16; o <<= 1) { s += __shfl_xor(s, o); q += __shfl_xor(q, o); }
        float mu = s * (1.f / DM);
        float var = q * (1.f / DM) - mu * mu;
        float rs = rsqrtf(var + LN_EPS);
        float4 o0, o1;
        o0.x = (v[0] - mu) * rs * nw[l * DM + tx * 8 + 0] + nb[l * DM + tx * 8 + 0];
        o0.y = (v[1] - mu) * rs * nw[l * DM + tx * 8 + 1] + nb[l * DM + tx * 8 + 1];
        o0.z = (v[2] - mu) * rs * nw[l * DM + tx * 8 + 2] + nb[l * DM + tx * 8 + 2];
        o0.w = (v[3] - mu) * rs * nw[l * DM + tx * 8 + 3] + nb[l * DM + tx * 8 + 3];
        o1.x = (v[4] - mu) * rs * nw[l * DM + tx * 8 + 4] + nb[l * DM + tx * 8 + 4];
        o1.y = (v[5] - mu) * rs * nw[l * DM + tx * 8 + 5] + nb[l * DM + tx * 8 + 5];
        o1.z = (v[6] - mu) * rs * nw[l * DM + tx * 8 + 6] + nb[l * DM + tx * 8 + 6];
        o1.w = (v[7] - mu) * rs * nw[l * DM + tx * 8 + 7] + nb[l * DM + tx * 8 + 7];
        *(float4*)&h[(size_t)row * DM + tx * 8] = o0;
        *(float4*)&h[(size_t)row * DM + tx * 8 + 4] = o1;
    }
}

// ============ kernel 7: final layernorm + mean over T (parallel tokens) ============
__global__ __launch_bounds__(256) void k_final(const float* __restrict__ h,
                                               const float* __restrict__ ow,
                                               const float* __restrict__ ob,
                                               float* __restrict__ out) {
    const int n = blockIdx.x >> 2;
    const int quarter = blockIdx.x & 3;
    const int wave = threadIdx.x >> 6, lane = threadIdx.x & 63;
    const float w0 = ow[lane], w1 = ow[lane + 64];
    const float b0 = ob[lane], b1 = ob[lane + 64];
    float a0 = 0.f, a1 = 0.f;
    const int t0 = quarter * 64 + wave * 16;
#pragma unroll 4
    for (int i = 0; i < 16; ++i) {
        const float* row = h + ((size_t)n * TT + t0 + i) * DM;
        float v0 = row[lane], v1 = row[lane + 64];
        float s = v0 + v1, q = v0 * v0 + v1 * v1;
#pragma unroll
        for (int o = 1; o < 64; o <<= 1) { s += __shfl_xor(s, o); q += __shfl_xor(q, o); }
        float mu = s * (1.f / DM);
        float var = q * (1.f / DM) - mu * mu;
        float rs = rsqrtf(var + LN_EPS);
        a0 += (v0 - mu) * rs * w0 + b0;
        a1 += (v1 - mu) * rs * w1 + b1;
    }
    atomicAdd(&out[n * DM + lane], a0 * (1.f / TT));
    atomicAdd(&out[n * DM + lane + 64], a1 * (1.f / TT));
}

extern "C" void kernel_launch(void* const* d_in, const int* in_sizes, int n_in,
                              void* d_out, int out_size, void* d_ws, size_t ws_size,
                              hipStream_t stream) {
    const float* x     = (const float*)d_in[0];
    const float* inp_w = (const float*)d_in[1];
    const float* inp_b = (const float*)d_in[2];
    const float* ipw   = (const float*)d_in[3];
    const float* cw    = (const float*)d_in[4];
    const float* cb    = (const float*)d_in[5];
    const float* xpw   = (const float*)d_in[6];
    const float* dtw   = (const float*)d_in[7];
    const float* dtb   = (const float*)d_in[8];
    const float* alog  = (const float*)d_in[9];
    const float* Dv    = (const float*)d_in[10];
    const float* opw   = (const float*)d_in[11];
    const float* nw    = (const float*)d_in[12];
    const float* nb    = (const float*)d_in[13];
    const float* onw   = (const float*)d_in[14];
    const float* onb   = (const float*)d_in[15];

    float* base = (float*)d_ws;
    const size_t NT = (size_t)NSEQ * TT;
    float* h    = base;
    float* xz   = h + NT * DM;
    float* u    = xz + NT * 2 * DI;
    float* xdbl = u + NT * DI;

    k_input_proj<<<NT / 64, 256, 0, stream>>>(x, inp_w, inp_b, h);
    for (int l = 0; l < 2; ++l) {
        k_in_proj<<<(NT / 64) * 8, 256, 0, stream>>>(h, ipw, xz, l);
        k_conv<<<NT, 256, 0, stream>>>(xz, cw, cb, u, l);
        k_xd<<<NT, 320, 0, stream>>>(u, xpw, dtw, dtb, xdbl, xz, l);
        k_scan<<<NSEQ * 8, 256, 0, stream>>>(xz, u, xdbl, alog, Dv, l);
        k_outproj_ln<<<NT / 64, 256, 0, stream>>>(u, opw, h, nw, nb, l);
    }
    hipMemsetAsync(d_out, 0, (size_t)out_size * sizeof(float), stream);
    k_final<<<NSEQ * 4, 256, 0, stream>>>(h, onw, onb, (float*)d_out);
}

// Round 9
// 453.388 us; speedup vs baseline: 1.0871x; 1.0421x over previous
//
#include <hip/hip_runtime.h>
#include <stdint.h>

#define NSEQ 64      // B*C
#define TT   256
#define FF   64
#define DM   128
#define DI   256
#define DS   16
#define DTR  8
#define XDBL 40      // DTR + 2*DS
#define LN_EPS 1e-5f

__device__ __forceinline__ float silu(float v) { return v / (1.f + __expf(-v)); }

// ============ kernel 1: input projection GEMM ============
__global__ __launch_bounds__(256) void k_input_proj(const float* __restrict__ x,
                                                    const float* __restrict__ w,
                                                    const float* __restrict__ b,
                                                    float* __restrict__ h) {
    __shared__ float As[FF][68];    // As[f][local_t]
    __shared__ float Bs[FF][132];   // Bs[f][dm]
    const int m0 = blockIdx.x * 64;
    const int n = m0 >> 8, t0 = m0 & 255;
    const int tid = threadIdx.x;
    {
        const int tq = tid & 15, f0 = tid >> 4;
#pragma unroll
        for (int i = 0; i < 4; ++i) {
            int f = f0 + 16 * i;
            float4 v = *(const float4*)&x[((size_t)n * FF + f) * TT + t0 + 4 * tq];
            *(float4*)&As[f][4 * tq] = v;
        }
#pragma unroll
        for (int i = 0; i < 8; ++i) {
            int col = f0 + 16 * i;
            float4 v = *(const float4*)&w[(size_t)col * FF + 4 * tq];
            Bs[4 * tq + 0][col] = v.x; Bs[4 * tq + 1][col] = v.y;
            Bs[4 * tq + 2][col] = v.z; Bs[4 * tq + 3][col] = v.w;
        }
    }
    __syncthreads();
    const int ty = tid >> 4, tx = tid & 15;
    float acc[4][8];
#pragma unroll
    for (int r = 0; r < 4; ++r)
#pragma unroll
        for (int c = 0; c < 8; ++c) acc[r][c] = 0.f;
#pragma unroll 8
    for (int k = 0; k < FF; ++k) {
        float4 a = *(float4*)&As[k][ty * 4];
        float4 b0 = *(float4*)&Bs[k][tx * 8];
        float4 b1 = *(float4*)&Bs[k][tx * 8 + 4];
        float av[4] = {a.x, a.y, a.z, a.w};
        float bv[8] = {b0.x, b0.y, b0.z, b0.w, b1.x, b1.y, b1.z, b1.w};
#pragma unroll
        for (int r = 0; r < 4; ++r)
#pragma unroll
            for (int c = 0; c < 8; ++c) acc[r][c] += av[r] * bv[c];
    }
#pragma unroll
    for (int r = 0; r < 4; ++r) {
        int row = m0 + ty * 4 + r;
        float4 o0, o1;
        o0.x = acc[r][0] + b[tx * 8 + 0]; o0.y = acc[r][1] + b[tx * 8 + 1];
        o0.z = acc[r][2] + b[tx * 8 + 2]; o0.w = acc[r][3] + b[tx * 8 + 3];
        o1.x = acc[r][4] + b[tx * 8 + 4]; o1.y = acc[r][5] + b[tx * 8 + 5];
        o1.z = acc[r][6] + b[tx * 8 + 6]; o1.w = acc[r][7] + b[tx * 8 + 7];
        *(float4*)&h[(size_t)row * DM + tx * 8] = o0;
        *(float4*)&h[(size_t)row * DM + tx * 8 + 4] = o1;
    }
}

// ============ kernel 2: in_proj GEMM ============
__global__ __launch_bounds__(256) void k_in_proj(const float* __restrict__ h,
                                                 const float* __restrict__ ipw,
                                                 float* __restrict__ xz, int l) {
    __shared__ float As[64][68];
    __shared__ float Bs[64][68];
    const int m0 = (blockIdx.x >> 3) * 64;
    const int n0 = (blockIdx.x & 7) * 64;
    const int tid = threadIdx.x;
    const int ty = tid >> 4, tx = tid & 15;
    const float* wbase = ipw + (size_t)l * 2 * DI * DM;
    float acc[4][4];
#pragma unroll
    for (int r = 0; r < 4; ++r)
#pragma unroll
        for (int c = 0; c < 4; ++c) acc[r][c] = 0.f;

    for (int k0 = 0; k0 < DM; k0 += 64) {
        const int kq = tid & 15, r0 = tid >> 4;
#pragma unroll
        for (int i = 0; i < 4; ++i) {
            int row = r0 + 16 * i;
            float4 v = *(const float4*)&h[(size_t)(m0 + row) * DM + k0 + 4 * kq];
            As[4 * kq + 0][row] = v.x; As[4 * kq + 1][row] = v.y;
            As[4 * kq + 2][row] = v.z; As[4 * kq + 3][row] = v.w;
            float4 wv = *(const float4*)&wbase[(size_t)(n0 + row) * DM + k0 + 4 * kq];
            Bs[4 * kq + 0][row] = wv.x; Bs[4 * kq + 1][row] = wv.y;
            Bs[4 * kq + 2][row] = wv.z; Bs[4 * kq + 3][row] = wv.w;
        }
        __syncthreads();
#pragma unroll 8
        for (int k = 0; k < 64; ++k) {
            float4 a = *(float4*)&As[k][ty * 4];
            float4 b = *(float4*)&Bs[k][tx * 4];
            float av[4] = {a.x, a.y, a.z, a.w};
            float bv[4] = {b.x, b.y, b.z, b.w};
#pragma unroll
            for (int r = 0; r < 4; ++r)
#pragma unroll
                for (int c = 0; c < 4; ++c) acc[r][c] += av[r] * bv[c];
        }
        __syncthreads();
    }
#pragma unroll
    for (int r = 0; r < 4; ++r) {
        int row = m0 + ty * 4 + r;
        float4 o = {acc[r][0], acc[r][1], acc[r][2], acc[r][3]};
        *(float4*)&xz[(size_t)row * (2 * DI) + n0 + tx * 4] = o;
    }
}

// ============ kernel 3: causal depthwise conv + silu -> u ============
__global__ __launch_bounds__(256) void k_conv(const float* __restrict__ xz,
                                              const float* __restrict__ cw,
                                              const float* __restrict__ cb,
                                              float* __restrict__ u, int l) {
    int idx = blockIdx.x * 256 + threadIdx.x;
    int d = idx & (DI - 1);
    int nt = idx >> 8;
    int t = nt & 255;
    const float* wr = cw + ((size_t)l * DI + d) * 4;
    float acc = cb[l * DI + d];
#pragma unroll
    for (int j = 0; j < 4; ++j) {
        int back = 3 - j;
        if (t - back >= 0)
            acc += xz[(size_t)(nt - back) * (2 * DI) + d] * wr[j];
    }
    u[(size_t)nt * DI + d] = silu(acc);
}

// ============ kernel 4: x_dbl + delta (delta -> xi slot of xz) ============
__global__ __launch_bounds__(320) void k_xd(const float* __restrict__ u,
                                            const float* __restrict__ xpw,
                                            const float* __restrict__ dtw,
                                            const float* __restrict__ dtb,
                                            float* __restrict__ xdbl,
                                            float* __restrict__ xz, int l) {
    __shared__ float us[DI];
    __shared__ float xd[XDBL];
    const int nt = blockIdx.x, tid = threadIdx.x;
    if (tid < 64)
        *(float4*)&us[tid * 4] = *(const float4*)&u[(size_t)nt * DI + tid * 4];
    __syncthreads();
    {
        const int g = tid >> 3, i = tid & 7;
        const float* wr = xpw + ((size_t)l * XDBL + g) * DI;
        float p = 0.f;
#pragma unroll
        for (int q = 0; q < 8; ++q) {
            int k = i * 4 + 32 * q;
            float4 uv = *(float4*)&us[k];
            float4 wv = *(const float4*)&wr[k];
            p += uv.x * wv.x + uv.y * wv.y + uv.z * wv.z + uv.w * wv.w;
        }
        p += __shfl_xor(p, 1); p += __shfl_xor(p, 2); p += __shfl_xor(p, 4);
        if (i == 0) { xd[g] = p; xdbl[(size_t)nt * XDBL + g] = p; }
    }
    __syncthreads();
    if (tid < DI) {
        const float* dwr = dtw + ((size_t)l * DI + tid) * DTR;
        float a = dtb[l * DI + tid];
#pragma unroll
        for (int r = 0; r < DTR; ++r) a += xd[r] * dwr[r];
        float sp = (a > 20.f) ? a : log1pf(__expf(a));
        xz[(size_t)nt * (2 * DI) + tid] = sp;
    }
}

// ============ kernel 5: selective scan (einsum only), sg=4, depth-8 prefetch ========
// grid = NSEQ*4 (n, d-quarter), block = 256 = 64 channels x 4 state-groups
// delta read from xi slot of xz; RAW y_pre written back over the same slot
// (safe: per-(t,d) owner thread; stores at t<=tb+7 precede prefetch reads at t>=tb+8)
__global__ __launch_bounds__(256) void k_scan(float* __restrict__ xz,
                                              const float* __restrict__ u,
                                              const float* __restrict__ xdbl,
                                              const float* __restrict__ alog, int l) {
    const int n = blockIdx.x >> 2;
    const int d = (blockIdx.x & 3) * 64 + (threadIdx.x >> 2);
    const int sg = threadIdx.x & 3;          // states sg*4..sg*4+3
    __shared__ float Bs[TT * DS];
    __shared__ float Cs[TT * DS];
    for (int i = threadIdx.x; i < TT * 4; i += 256) {
        int t = i >> 2, sq = i & 3;
        const float* row = xdbl + ((size_t)n * TT + t) * XDBL;
        *(float4*)&Bs[t * DS + 4 * sq] = *(const float4*)&row[DTR + 4 * sq];
        *(float4*)&Cs[t * DS + 4 * sq] = *(const float4*)&row[DTR + DS + 4 * sq];
    }
    __syncthreads();
    float4 av = *(const float4*)&alog[((size_t)l * DI + d) * DS + sg * 4];
    float A[4] = {-__expf(av.x), -__expf(av.y), -__expf(av.z), -__expf(av.w)};
    float hst[4] = {0.f, 0.f, 0.f, 0.f};

    float* dlt_p = xz + (size_t)n * TT * (2 * DI) + d;   // delta in, y_pre out
    const float* uv_p = u + (size_t)n * TT * DI + d;

    float pD[8], pU[8];
#pragma unroll
    for (int j = 0; j < 8; ++j) {
        pD[j] = dlt_p[(size_t)j * (2 * DI)];
        pU[j] = uv_p[(size_t)j * DI];
    }
    for (int tb = 0; tb < TT; tb += 8) {
        float cD[8], cU[8];
#pragma unroll
        for (int j = 0; j < 8; ++j) { cD[j] = pD[j]; cU[j] = pU[j]; }
        const int tn0 = (tb + 8) & 255;      // wraps on last group; values unused
#pragma unroll
        for (int j = 0; j < 8; ++j) {
            size_t tn = (size_t)(tn0 + j);
            pD[j] = dlt_p[tn * (2 * DI)];
            pU[j] = uv_p[tn * DI];
        }
#pragma unroll
        for (int j = 0; j < 8; ++j) {
            const int t = tb + j;
            float dlt = cD[j];
            float du = dlt * cU[j];
            const float* bt = Bs + t * DS + sg * 4;
            const float* ct = Cs + t * DS + sg * 4;
            float y = 0.f;
#pragma unroll
            for (int s = 0; s < 4; ++s) {
                float dA = __expf(dlt * A[s]);
                hst[s] = dA * hst[s] + du * bt[s];
                y += hst[s] * ct[s];
            }
            y += __shfl_xor(y, 1);
            y += __shfl_xor(y, 2);
            if (sg == 0)
                dlt_p[(size_t)t * (2 * DI)] = y;   // raw einsum result
        }
    }
}

// ============ kernel 6: gate + out_proj GEMM + residual + layernorm ============
// A-staging applies v = (y_pre + u*D) * silu(z) on the fly
__global__ __launch_bounds__(256) void k_outproj_ln(const float* __restrict__ xz,
                                                    const float* __restrict__ u,
                                                    const float* __restrict__ Dvec,
                                                    const float* __restrict__ opw,
                                                    float* __restrict__ h,
                                                    const float* __restrict__ nw,
                                                    const float* __restrict__ nb, int l) {
    __shared__ float As[64][68];
    __shared__ float Bs[64][132];
    const int m0 = blockIdx.x * 64;
    const int tid = threadIdx.x;
    const int ty = tid >> 4, tx = tid & 15;
    const float* wbase = opw + (size_t)l * DM * DI;
    float acc[4][8];
#pragma unroll
    for (int r = 0; r < 4; ++r)
#pragma unroll
        for (int c = 0; c < 8; ++c) acc[r][c] = 0.f;

    for (int k0 = 0; k0 < DI; k0 += 64) {
        const int kq = tid & 15, r0 = tid >> 4;
        float4 dv = *(const float4*)&Dvec[l * DI + k0 + 4 * kq];
#pragma unroll
        for (int i = 0; i < 4; ++i) {
            int row = r0 + 16 * i;
            size_t m = (size_t)(m0 + row);
            float4 yv = *(const float4*)&xz[m * (2 * DI) + k0 + 4 * kq];        // y_pre
            float4 uv = *(const float4*)&u[m * DI + k0 + 4 * kq];
            float4 zv = *(const float4*)&xz[m * (2 * DI) + DI + k0 + 4 * kq];   // z
            float4 v;
            v.x = (yv.x + uv.x * dv.x) * silu(zv.x);
            v.y = (yv.y + uv.y * dv.y) * silu(zv.y);
            v.z = (yv.z + uv.z * dv.z) * silu(zv.z);
            v.w = (yv.w + uv.w * dv.w) * silu(zv.w);
            As[4 * kq + 0][row] = v.x; As[4 * kq + 1][row] = v.y;
            As[4 * kq + 2][row] = v.z; As[4 * kq + 3][row] = v.w;
        }
#pragma unroll
        for (int i = 0; i < 8; ++i) {
            int col = r0 + 16 * i;
            float4 wv = *(const float4*)&wbase[(size_t)col * DI + k0 + 4 * kq];
            Bs[4 * kq + 0][col] = wv.x; Bs[4 * kq + 1][col] = wv.y;
            Bs[4 * kq + 2][col] = wv.z; Bs[4 * kq + 3][col] = wv.w;
        }
        __syncthreads();
#pragma unroll 8
        for (int k = 0; k < 64; ++k) {
            float4 a = *(float4*)&As[k][ty * 4];
            float4 b0 = *(float4*)&Bs[k][tx * 8];
            float4 b1 = *(float4*)&Bs[k][tx * 8 + 4];
            float av[4] = {a.x, a.y, a.z, a.w};
            float bv[8] = {b0.x, b0.y, b0.z, b0.w, b1.x, b1.y, b1.z, b1.w};
#pragma unroll
            for (int r = 0; r < 4; ++r)
#pragma unroll
                for (int c = 0; c < 8; ++c) acc[r][c] += av[r] * bv[c];
        }
        __syncthreads();
    }
#pragma unroll
    for (int r = 0; r < 4; ++r) {
        int row = m0 + ty * 4 + r;
        float4 h0 = *(float4*)&h[(size_t)row * DM + tx * 8];
        float4 h1 = *(float4*)&h[(size_t)row * DM + tx * 8 + 4];
        float v[8] = {acc[r][0] + h0.x, acc[r][1] + h0.y, acc[r][2] + h0.z, acc[r][3] + h0.w,
                      acc[r][4] + h1.x, acc[r][5] + h1.y, acc[r][6] + h1.z, acc[r][7] + h1.w};
        float s = 0.f, q = 0.f;
#pragma unroll
        for (int c = 0; c < 8; ++c) { s += v[c]; q += v[c] * v[c]; }
#pragma unroll
        for (int o = 1; o < 16; o <<= 1) { s += __shfl_xor(s, o); q += __shfl_xor(q, o); }
        float mu = s * (1.f / DM);
        float var = q * (1.f / DM) - mu * mu;
        float rs = rsqrtf(var + LN_EPS);
        float4 o0, o1;
        o0.x = (v[0] - mu) * rs * nw[l * DM + tx * 8 + 0] + nb[l * DM + tx * 8 + 0];
        o0.y = (v[1] - mu) * rs * nw[l * DM + tx * 8 + 1] + nb[l * DM + tx * 8 + 1];
        o0.z = (v[2] - mu) * rs * nw[l * DM + tx * 8 + 2] + nb[l * DM + tx * 8 + 2];
        o0.w = (v[3] - mu) * rs * nw[l * DM + tx * 8 + 3] + nb[l * DM + tx * 8 + 3];
        o1.x = (v[4] - mu) * rs * nw[l * DM + tx * 8 + 4] + nb[l * DM + tx * 8 + 4];
        o1.y = (v[5] - mu) * rs * nw[l * DM + tx * 8 + 5] + nb[l * DM + tx * 8 + 5];
        o1.z = (v[6] - mu) * rs * nw[l * DM + tx * 8 + 6] + nb[l * DM + tx * 8 + 6];
        o1.w = (v[7] - mu) * rs * nw[l * DM + tx * 8 + 7] + nb[l * DM + tx * 8 + 7];
        *(float4*)&h[(size_t)row * DM + tx * 8] = o0;
        *(float4*)&h[(size_t)row * DM + tx * 8 + 4] = o1;
    }
}

// ============ kernel 7: final layernorm + mean over T (parallel tokens) ============
__global__ __launch_bounds__(256) void k_final(const float* __restrict__ h,
                                               const float* __restrict__ ow,
                                               const float* __restrict__ ob,
                                               float* __restrict__ out) {
    const int n = blockIdx.x >> 2;
    const int quarter = blockIdx.x & 3;
    const int wave = threadIdx.x >> 6, lane = threadIdx.x & 63;
    const float w0 = ow[lane], w1 = ow[lane + 64];
    const float b0 = ob[lane], b1 = ob[lane + 64];
    float a0 = 0.f, a1 = 0.f;
    const int t0 = quarter * 64 + wave * 16;
#pragma unroll 4
    for (int i = 0; i < 16; ++i) {
        const float* row = h + ((size_t)n * TT + t0 + i) * DM;
        float v0 = row[lane], v1 = row[lane + 64];
        float s = v0 + v1, q = v0 * v0 + v1 * v1;
#pragma unroll
        for (int o = 1; o < 64; o <<= 1) { s += __shfl_xor(s, o); q += __shfl_xor(q, o); }
        float mu = s * (1.f / DM);
        float var = q * (1.f / DM) - mu * mu;
        float rs = rsqrtf(var + LN_EPS);
        a0 += (v0 - mu) * rs * w0 + b0;
        a1 += (v1 - mu) * rs * w1 + b1;
    }
    atomicAdd(&out[n * DM + lane], a0 * (1.f / TT));
    atomicAdd(&out[n * DM + lane + 64], a1 * (1.f / TT));
}

extern "C" void kernel_launch(void* const* d_in, const int* in_sizes, int n_in,
                              void* d_out, int out_size, void* d_ws, size_t ws_size,
                              hipStream_t stream) {
    const float* x     = (const float*)d_in[0];
    const float* inp_w = (const float*)d_in[1];
    const float* inp_b = (const float*)d_in[2];
    const float* ipw   = (const float*)d_in[3];
    const float* cw    = (const float*)d_in[4];
    const float* cb    = (const float*)d_in[5];
    const float* xpw   = (const float*)d_in[6];
    const float* dtw   = (const float*)d_in[7];
    const float* dtb   = (const float*)d_in[8];
    const float* alog  = (const float*)d_in[9];
    const float* Dv    = (const float*)d_in[10];
    const float* opw   = (const float*)d_in[11];
    const float* nw    = (const float*)d_in[12];
    const float* nb    = (const float*)d_in[13];
    const float* onw   = (const float*)d_in[14];
    const float* onb   = (const float*)d_in[15];

    float* base = (float*)d_ws;
    const size_t NT = (size_t)NSEQ * TT;
    float* h    = base;                 // NT*128
    float* xz   = h + NT * DM;          // NT*512  [xi -> delta -> y_pre | z]
    float* u    = xz + NT * 2 * DI;     // NT*256  conv+silu output (preserved)
    float* xdbl = u + NT * DI;          // NT*40

    k_input_proj<<<NT / 64, 256, 0, stream>>>(x, inp_w, inp_b, h);
    for (int l = 0; l < 2; ++l) {
        k_in_proj<<<(NT / 64) * 8, 256, 0, stream>>>(h, ipw, xz, l);
        k_conv<<<NT, 256, 0, stream>>>(xz, cw, cb, u, l);
        k_xd<<<NT, 320, 0, stream>>>(u, xpw, dtw, dtb, xdbl, xz, l);
        k_scan<<<NSEQ * 4, 256, 0, stream>>>(xz, u, xdbl, alog, l);
        k_outproj_ln<<<NT / 64, 256, 0, stream>>>(xz, u, Dv, opw, h, nw, nb, l);
    }
    hipMemsetAsync(d_out, 0, (size_t)out_size * sizeof(float), stream);
    k_final<<<NSEQ * 4, 256, 0, stream>>>(h, onw, onb, (float*)d_out);
}